// Round 1
// 198.204 us; speedup vs baseline: 1.0859x; 1.0859x over previous
//
#include <hip/hip_runtime.h>
#include <math.h>

// ---------------------------------------------------------------------------
// HROMAttention: x(4,2048,512) -> QKV(+bias) -> RoPE -> MHA(8 heads, d=64)
//                -> proj(+bias). All GEMMs bf16 MFMA 16x16x32, fp32 accum.
// Round 3: attn rework for occupancy + VALU:
//   - 512-thread blocks (8 waves x 16 q) -> 16 waves/CU (was 8)
//   - v_cvt_pk_bf16_f32 for P-pack + epilogue (1 inst / 2 values)
//   - defer-rescale: skip alpha/exp2/O-rescale when no lane's max grew (exact)
//   - unpadded 64-short LDS rows with XOR swizzle (col ^ ((row&7)<<3)) for
//     Ks/Vs/Ps -> bank-conflict-free b128 reads, LDS 36KB -> 32KB
// ws layout (bytes):
//   [0)         xb     bf16 8192x512     8388608
//   [8388608)   wqb    bf16 1536x512     1572864
//   [9961472)   wpb    bf16  512x512      524288
//   [10485760)  cosT   f32  2048x32       262144
//   [10747904)  sinT   f32  2048x32       262144
//   [11010048)  Qb     bf16 (b,h,t,d)    8388608   (pre-scaled by 0.125*log2e)
//   [19398656)  Kb     bf16 (b,h,t,d)    8388608
//   [27787264)  Vtb    bf16 (b,h,d,t)    8388608
//   [36175872)  attnb  bf16 8192x512     8388608
// total 44564480 B (~42.5 MB) of d_ws
// ---------------------------------------------------------------------------

typedef __attribute__((ext_vector_type(8))) short bf16x8;
typedef __attribute__((ext_vector_type(4))) float floatx4;

#define LOG2E 1.44269504088896f

__device__ __forceinline__ unsigned short f2bf(float f) {
  unsigned int u = __float_as_uint(f);
  u += 0x7fffu + ((u >> 16) & 1u);   // round-to-nearest-even
  return (unsigned short)(u >> 16);
}

// pack two f32 -> bf16x2 (low16 = a, high16 = b), RNE, single VALU inst
__device__ __forceinline__ unsigned int cvtpk_bf16(float a, float b) {
  unsigned int r;
  asm("v_cvt_pk_bf16_f32 %0, %1, %2" : "=v"(r) : "v"(a), "v"(b));
  return r;
}

__device__ __forceinline__ void gld_lds16(unsigned short* lds, const unsigned short* g) {
  __builtin_amdgcn_global_load_lds(
      (const __attribute__((address_space(1))) unsigned int*)g,
      (__attribute__((address_space(3))) unsigned int*)lds, 16, 0, 0);
}

// ---------------------------------------------------------------------------
// prep: bf16 conversions + RoPE cos/sin table (fp64 trig for accuracy)
// ---------------------------------------------------------------------------
__global__ __launch_bounds__(256) void prep_kernel(
    const float* __restrict__ x, const float* __restrict__ wq, const float* __restrict__ wp,
    unsigned short* __restrict__ xb, unsigned short* __restrict__ wqb,
    unsigned short* __restrict__ wpb, float* __restrict__ cosT, float* __restrict__ sinT) {
  int i = blockIdx.x * 256 + threadIdx.x;
  if (i < 4194304) {
    xb[i] = f2bf(x[i]);
  } else if (i < 4980736) {
    int j = i - 4194304; wqb[j] = f2bf(wq[j]);
  } else if (i < 5242880) {
    int j = i - 4980736; wpb[j] = f2bf(wp[j]);
  } else if (i < 5308416) {
    int j = i - 5242880;
    int t = j >> 5, f = j & 31;
    double fr = (double)t * pow(10000.0, -(double)f / 32.0);
    cosT[j] = (float)cos(fr);
    sinT[j] = (float)sin(fr);
  }
}

// ---------------------------------------------------------------------------
// QKV GEMM: xb(8192x512) @ wqb(1536x512)^T + bias, epilogue RoPE + scatter
// 128x128 tile, BK=32, 4 waves each 64x64 (4x4 m/n tiles of 16x16)
// ---------------------------------------------------------------------------
__global__ __launch_bounds__(256) void qkv_kernel(
    const unsigned short* __restrict__ xb, const unsigned short* __restrict__ wqb,
    const float* __restrict__ qkv_b, const float* __restrict__ cosT,
    const float* __restrict__ sinT, unsigned short* __restrict__ Qb,
    unsigned short* __restrict__ Kb, unsigned short* __restrict__ Vtb) {
  __shared__ __align__(16) unsigned short As[128 * 32];
  __shared__ __align__(16) unsigned short Bs[128 * 32];
  const int tid = threadIdx.x;
  const int wave = tid >> 6, lane = tid & 63, ln = lane & 15, quad = lane >> 4;
  const int m0 = blockIdx.x * 128, n0 = blockIdx.y * 128;
  const int wr = (wave >> 1) * 64, wc = (wave & 1) * 64;

  floatx4 acc[4][4];
#pragma unroll
  for (int i = 0; i < 4; ++i)
#pragma unroll
    for (int j = 0; j < 4; ++j) acc[i][j] = (floatx4){0.f, 0.f, 0.f, 0.f};

  const int c0 = tid, c1 = tid + 256;
  const int ar0 = c0 >> 2, ak0 = (c0 & 3) * 8;
  const int ar1 = c1 >> 2, ak1 = (c1 & 3) * 8;

  for (int k0 = 0; k0 < 512; k0 += 32) {
    __syncthreads();
    gld_lds16(As + c0 * 8, xb + (size_t)(m0 + ar0) * 512 + k0 + ak0);
    gld_lds16(As + c1 * 8, xb + (size_t)(m0 + ar1) * 512 + k0 + ak1);
    gld_lds16(Bs + c0 * 8, wqb + (size_t)(n0 + ar0) * 512 + k0 + ak0);
    gld_lds16(Bs + c1 * 8, wqb + (size_t)(n0 + ar1) * 512 + k0 + ak1);
    __syncthreads();
    bf16x8 af[4], bfb[4];
#pragma unroll
    for (int mi = 0; mi < 4; ++mi)
      af[mi] = *(const bf16x8*)(As + (wr + mi * 16 + ln) * 32 + quad * 8);
#pragma unroll
    for (int ni = 0; ni < 4; ++ni)
      bfb[ni] = *(const bf16x8*)(Bs + (wc + ni * 16 + ln) * 32 + quad * 8);
#pragma unroll
    for (int mi = 0; mi < 4; ++mi)
#pragma unroll
      for (int ni = 0; ni < 4; ++ni)
        acc[mi][ni] = __builtin_amdgcn_mfma_f32_16x16x32_bf16(af[mi], bfb[ni], acc[mi][ni], 0, 0, 0);
  }

  // epilogue: wave's 64 cols lie in exactly one (mat, head)
  const int colbase = n0 + wc;                    // multiple of 64
  const int mat = colbase >> 9;                   // 0=q 1=k 2=v
  const int h = (colbase & 511) >> 6;
  float bias[4];
#pragma unroll
  for (int ni = 0; ni < 4; ++ni) bias[ni] = qkv_b[colbase + ni * 16 + ln];

  if (mat == 2) {
    // V: store transposed (b,h,d,t); lane holds 4 consecutive t at fixed d
#pragma unroll
    for (int mi = 0; mi < 4; ++mi) {
      int row0 = m0 + wr + mi * 16 + quad * 4;
      int bidx = row0 >> 11, t = row0 & 2047;
#pragma unroll
      for (int ni = 0; ni < 4; ++ni) {
        int d = ni * 16 + ln;
        ushort4 pk;
        pk.x = f2bf(acc[mi][ni][0] + bias[ni]);
        pk.y = f2bf(acc[mi][ni][1] + bias[ni]);
        pk.z = f2bf(acc[mi][ni][2] + bias[ni]);
        pk.w = f2bf(acc[mi][ni][3] + bias[ni]);
        *(ushort4*)(Vtb + ((size_t)(bidx * 8 + h) * 64 + d) * 2048 + t) = pk;
      }
    }
  } else {
    // Q/K: in-register RoPE — pair (d, d+32) = acc tiles (ni, ni+2), same lane
    unsigned short* dst = (mat == 0) ? Qb : Kb;
    // fold 1/sqrt(64) AND log2(e) (exp2-domain softmax) into Q
    const float sc = (mat == 0) ? 0.125f * LOG2E : 1.0f;
#pragma unroll
    for (int mi = 0; mi < 4; ++mi) {
#pragma unroll
      for (int r = 0; r < 4; ++r) {
        int row = m0 + wr + mi * 16 + quad * 4 + r;
        int bidx = row >> 11, t = row & 2047;
        const float* cr = cosT + t * 32;
        const float* sr = sinT + t * 32;
        size_t obase = ((size_t)(bidx * 8 + h) * 2048 + t) * 64;
#pragma unroll
        for (int ni = 0; ni < 2; ++ni) {
          int dlo = ni * 16 + ln;
          float cv = cr[dlo], sv = sr[dlo];
          float xlo = acc[mi][ni][r] + bias[ni];
          float xhi = acc[mi][ni + 2][r] + bias[ni + 2];
          dst[obase + dlo]      = f2bf((xlo * cv - xhi * sv) * sc);
          dst[obase + dlo + 32] = f2bf((xhi * cv + xlo * sv) * sc);
        }
      }
    }
  }
}

// ---------------------------------------------------------------------------
// Transposed flash attention, round 3:
//   block = 128 q x one (b,h); 8 waves x 16 q each; K-tile = 64.
//   S^T = K·Q^T so each lane owns one q-column.
//   LDS rows are 64 shorts (128 B), XOR-swizzled: physical col granule =
//   (col>>3) ^ (row&7); all b64/b128 accesses apply (col ^ ((row&7)<<3)).
//   P pack via v_cvt_pk_bf16_f32; O-rescale skipped when no max growth.
//   K/V staged via register prefetch (1 uint4 per thread per buffer).
// ---------------------------------------------------------------------------
__global__ __launch_bounds__(512) void attn_kernel(
    const unsigned short* __restrict__ Qb, const unsigned short* __restrict__ Kb,
    const unsigned short* __restrict__ Vtb, const float* __restrict__ mask,
    unsigned short* __restrict__ attnb) {
  __shared__ __align__(16) unsigned short Ks[64 * 64];   // (t_k, d)   swizzled
  __shared__ __align__(16) unsigned short Vs[64 * 64];   // (d, t_k)   swizzled
  __shared__ __align__(16) unsigned short Ps[128 * 64];  // (q, t_k)   swizzled

  const int tid = threadIdx.x;
  const int wave = tid >> 6, lane = tid & 63, ln = lane & 15, quad = lane >> 4;
  const int swz = (ln & 7) << 3;                 // row-derived XOR for frag reads
  const int bh = blockIdx.y;
  const int b = bh >> 3, h = bh & 7;
  const int q0 = blockIdx.x * 128;
  const int wq = wave * 16;                      // wave's local q base

  const unsigned short* Qhead = Qb + (size_t)bh * 2048 * 64;
  const unsigned short* Khead = Kb + (size_t)bh * 2048 * 64;
  const unsigned short* Vhead = Vtb + (size_t)bh * 64 * 2048;

  // Q B-frags, loaded once: B[n=q][k=d]
  bf16x8 qf[2];
#pragma unroll
  for (int ks = 0; ks < 2; ++ks)
    qf[ks] = *(const bf16x8*)(Qhead + (size_t)(q0 + wq + ln) * 64 + ks * 32 + quad * 8);

  floatx4 o[4];   // O^T: [d-tile], lane col = q
#pragma unroll
  for (int mi2 = 0; mi2 < 4; ++mi2) o[mi2] = (floatx4){0.f, 0.f, 0.f, 0.f};
  float mrun = -INFINITY;
  float lrun = 0.f;

  // staging map: thread covers one 16B chunk of K and one of V
  const int srow = tid >> 3;                     // 0..63
  const int scol = (tid & 7) * 8;                // shorts
  const int sdst = srow * 64 + (scol ^ ((srow & 7) << 3));
  uint4 kpre = *(const uint4*)(Khead + (size_t)srow * 64 + scol);
  uint4 vpre = *(const uint4*)(Vhead + (size_t)srow * 2048 + scol);

  for (int k0 = 0; k0 < 2048; k0 += 64) {
    __syncthreads();   // prev-iter Ks/Vs reads done
    *(uint4*)(Ks + sdst) = kpre;
    *(uint4*)(Vs + sdst) = vpre;
    __syncthreads();   // staging visible
    if (k0 + 64 < 2048) {   // prefetch next tile; latency hidden by compute
      kpre = *(const uint4*)(Khead + (size_t)(k0 + 64 + srow) * 64 + scol);
      vpre = *(const uint4*)(Vhead + (size_t)srow * 2048 + k0 + 64 + scol);
    }

    // S^T = K·Q^T : A=K-frag A[m=t_k][k=d], B=Q. C: row=t_k(quad*4+r), col=q(ln)
    floatx4 sm[4];
#pragma unroll
    for (int mi = 0; mi < 4; ++mi) {
      bf16x8 kf0 = *(const bf16x8*)(Ks + (mi * 16 + ln) * 64 + ((quad * 8) ^ swz));
      bf16x8 kf1 = *(const bf16x8*)(Ks + (mi * 16 + ln) * 64 + ((32 + quad * 8) ^ swz));
      floatx4 a = (floatx4){0.f, 0.f, 0.f, 0.f};
      a = __builtin_amdgcn_mfma_f32_16x16x32_bf16(kf0, qf[0], a, 0, 0, 0);
      a = __builtin_amdgcn_mfma_f32_16x16x32_bf16(kf1, qf[1], a, 0, 0, 0);
      sm[mi] = a;
    }
    // + mask (t_k varies over quad*4+r; exp2 domain -> * log2e)
#pragma unroll
    for (int mi = 0; mi < 4; ++mi) {
      float4 mv = *(const float4*)(mask + b * 2048 + k0 + mi * 16 + quad * 4);
      sm[mi][0] += mv.x * LOG2E; sm[mi][1] += mv.y * LOG2E;
      sm[mi][2] += mv.z * LOG2E; sm[mi][3] += mv.w * LOG2E;
    }
    // online softmax: per lane one q-column -> 15 in-reg max + 2 shuffles
    float vmax = fmaxf(fmaxf(sm[0][0], sm[0][1]), fmaxf(sm[0][2], sm[0][3]));
#pragma unroll
    for (int mi = 1; mi < 4; ++mi)
      vmax = fmaxf(vmax, fmaxf(fmaxf(sm[mi][0], sm[mi][1]), fmaxf(sm[mi][2], sm[mi][3])));
    vmax = fmaxf(vmax, __shfl_xor(vmax, 16));
    vmax = fmaxf(vmax, __shfl_xor(vmax, 32));
    // defer-rescale: only pay alpha/exp2/O-rescale when some lane's max grew.
    // When no lane grew, mrun stays == fmax(mrun, vmax) lane-wise -> exact skip.
    if (__any(vmax > mrun)) {
      float nm = fmaxf(mrun, vmax);
      float alpha = exp2f(mrun - nm);   // lanes w/o growth: exp2(0)=1
      mrun = nm;
      lrun *= alpha;
#pragma unroll
      for (int mi2 = 0; mi2 < 4; ++mi2) {
        o[mi2][0] *= alpha; o[mi2][1] *= alpha;
        o[mi2][2] *= alpha; o[mi2][3] *= alpha;
      }
    }
    float psum = 0.f;
#pragma unroll
    for (int mi = 0; mi < 4; ++mi)
#pragma unroll
      for (int r = 0; r < 4; ++r) {
        float p = exp2f(sm[mi][r] - mrun);
        sm[mi][r] = p;
        psum += p;
      }
    psum += __shfl_xor(psum, 16);
    psum += __shfl_xor(psum, 32);
    lrun += psum;

    // P^T -> LDS (q, t_k): cvt_pk packed b64, per-wave rows, no barrier needed
#pragma unroll
    for (int mi = 0; mi < 4; ++mi) {
      uint2 pk;
      pk.x = cvtpk_bf16(sm[mi][0], sm[mi][1]);
      pk.y = cvtpk_bf16(sm[mi][2], sm[mi][3]);
      *(uint2*)(Ps + (wq + ln) * 64 + ((mi * 16 + quad * 4) ^ swz)) = pk;
    }
    // O^T += V^T·P : A=Vt-frag A[m=d][k=t_k], B=P-frag B[n=q][k=t_k]
#pragma unroll
    for (int ks = 0; ks < 2; ++ks) {
      bf16x8 pb = *(const bf16x8*)(Ps + (wq + ln) * 64 + ((ks * 32 + quad * 8) ^ swz));
#pragma unroll
      for (int mi2 = 0; mi2 < 4; ++mi2) {
        bf16x8 vf = *(const bf16x8*)(Vs + (mi2 * 16 + ln) * 64 + ((ks * 32 + quad * 8) ^ swz));
        o[mi2] = __builtin_amdgcn_mfma_f32_16x16x32_bf16(vf, pb, o[mi2], 0, 0, 0);
      }
    }
  }

  // epilogue: O^T lane owns q-col (1/l per-lane), 4 consecutive d per store
  {
    float inv = 1.f / lrun;
    int t = q0 + wq + ln;
    size_t base = ((size_t)b * 2048 + t) * 512 + h * 64;
#pragma unroll
    for (int mi2 = 0; mi2 < 4; ++mi2) {
      uint2 pk;
      pk.x = cvtpk_bf16(o[mi2][0] * inv, o[mi2][1] * inv);
      pk.y = cvtpk_bf16(o[mi2][2] * inv, o[mi2][3] * inv);
      *(uint2*)(attnb + base + mi2 * 16 + quad * 4) = pk;
    }
  }
}

// ---------------------------------------------------------------------------
// proj GEMM: attnb(8192x512) @ wpb(512x512)^T + bias -> out fp32
// ---------------------------------------------------------------------------
__global__ __launch_bounds__(256) void proj_kernel(
    const unsigned short* __restrict__ ab, const unsigned short* __restrict__ wpb,
    const float* __restrict__ proj_b, float* __restrict__ out) {
  __shared__ __align__(16) unsigned short As[128 * 32];
  __shared__ __align__(16) unsigned short Bs[128 * 32];
  const int tid = threadIdx.x;
  const int wave = tid >> 6, lane = tid & 63, ln = lane & 15, quad = lane >> 4;
  const int m0 = blockIdx.x * 128, n0 = blockIdx.y * 128;
  const int wr = (wave >> 1) * 64, wc = (wave & 1) * 64;

  floatx4 acc[4][4];
#pragma unroll
  for (int i = 0; i < 4; ++i)
#pragma unroll
    for (int j = 0; j < 4; ++j) acc[i][j] = (floatx4){0.f, 0.f, 0.f, 0.f};

  const int c0 = tid, c1 = tid + 256;
  const int ar0 = c0 >> 2, ak0 = (c0 & 3) * 8;
  const int ar1 = c1 >> 2, ak1 = (c1 & 3) * 8;

  for (int k0 = 0; k0 < 512; k0 += 32) {
    __syncthreads();
    gld_lds16(As + c0 * 8, ab + (size_t)(m0 + ar0) * 512 + k0 + ak0);
    gld_lds16(As + c1 * 8, ab + (size_t)(m0 + ar1) * 512 + k0 + ak1);
    gld_lds16(Bs + c0 * 8, wpb + (size_t)(n0 + ar0) * 512 + k0 + ak0);
    gld_lds16(Bs + c1 * 8, wpb + (size_t)(n0 + ar1) * 512 + k0 + ak1);
    __syncthreads();
    bf16x8 af[4], bfb[4];
#pragma unroll
    for (int mi = 0; mi < 4; ++mi)
      af[mi] = *(const bf16x8*)(As + (wr + mi * 16 + ln) * 32 + quad * 8);
#pragma unroll
    for (int ni = 0; ni < 4; ++ni)
      bfb[ni] = *(const bf16x8*)(Bs + (wc + ni * 16 + ln) * 32 + quad * 8);
#pragma unroll
    for (int mi = 0; mi < 4; ++mi)
#pragma unroll
      for (int ni = 0; ni < 4; ++ni)
        acc[mi][ni] = __builtin_amdgcn_mfma_f32_16x16x32_bf16(af[mi], bfb[ni], acc[mi][ni], 0, 0, 0);
  }

#pragma unroll
  for (int mi = 0; mi < 4; ++mi)
#pragma unroll
    for (int ni = 0; ni < 4; ++ni) {
      int col = n0 + wc + ni * 16 + ln;
      float pb = proj_b[col];
#pragma unroll
      for (int r = 0; r < 4; ++r) {
        int row = m0 + wr + mi * 16 + quad * 4 + r;
        out[(size_t)row * 512 + col] = acc[mi][ni][r] + pb;
      }
    }
}

// ---------------------------------------------------------------------------
extern "C" void kernel_launch(void* const* d_in, const int* in_sizes, int n_in,
                              void* d_out, int out_size, void* d_ws, size_t ws_size,
                              hipStream_t stream) {
  const float* x      = (const float*)d_in[0];
  const float* mask   = (const float*)d_in[1];
  const float* qkv_w  = (const float*)d_in[2];
  const float* qkv_b  = (const float*)d_in[3];
  const float* proj_w = (const float*)d_in[4];
  const float* proj_b = (const float*)d_in[5];
  float* out = (float*)d_out;

  char* ws = (char*)d_ws;
  unsigned short* xb   = (unsigned short*)(ws);
  unsigned short* wqb  = (unsigned short*)(ws + 8388608);
  unsigned short* wpb  = (unsigned short*)(ws + 9961472);
  float* cosT          = (float*)(ws + 10485760);
  float* sinT          = (float*)(ws + 10747904);
  unsigned short* Qb   = (unsigned short*)(ws + 11010048);
  unsigned short* Kb   = (unsigned short*)(ws + 19398656);
  unsigned short* Vtb  = (unsigned short*)(ws + 27787264);
  unsigned short* attnb= (unsigned short*)(ws + 36175872);

  prep_kernel<<<20736, 256, 0, stream>>>(x, qkv_w, proj_w, xb, wqb, wpb, cosT, sinT);
  dim3 g1(64, 12);
  qkv_kernel<<<g1, 256, 0, stream>>>(xb, wqb, qkv_b, cosT, sinT, Qb, Kb, Vtb);
  dim3 g2(16, 32);
  attn_kernel<<<g2, 512, 0, stream>>>(Qb, Kb, Vtb, mask, attnb);
  dim3 g3(64, 4);
  proj_kernel<<<g3, 256, 0, stream>>>(attnb, wpb, proj_b, out);
}